// Round 13
// baseline (27.520 us; speedup 1.0000x reference)
//
#include <hip/hip_runtime.h>

#define D 64
#define STR 72    // LDS row stride in bf16 elems
#define WAVES 4   // independent waves per block, one sequence each

typedef __attribute__((ext_vector_type(8))) short bf16x8;
typedef __attribute__((ext_vector_type(4))) short bf16x4;
typedef __attribute__((ext_vector_type(4))) float f32x4;
typedef __attribute__((ext_vector_type(4))) unsigned int u32x4;
typedef __attribute__((ext_vector_type(2))) unsigned int u32x2;

static __device__ __forceinline__ unsigned short f2bf(float f) {
  unsigned u = __builtin_bit_cast(unsigned, f);
  u += 0x7fffu + ((u >> 16) & 1u);  // RNE
  return (unsigned short)(u >> 16);
}

// wave-private LDS ordering (staging ds_writes -> fragment ds_reads)
#define LDSWAIT() asm volatile("s_waitcnt lgkmcnt(0)" ::: "memory")

// K=16 bf16 MFMA (v_mfma_f32_16x16x16_bf16, cdna4_isa §10; LLVM spelling is
// the gfx90a-carried _1k builtin). r12 failed on the HOST pass: __has_builtin
// of amdgcn builtins is 0 there. Gate on __HIP_DEVICE_COMPILE__ instead —
// host only needs to parse, never execute.
static __device__ __forceinline__ f32x4 mfma16(bf16x4 a, bf16x4 b, f32x4 c) {
#if defined(__HIP_DEVICE_COMPILE__)
  return __builtin_amdgcn_mfma_f32_16x16x16bf16_1k(a, b, c, 0, 0, 0);
#else
  return c;  // host parse-only dummy
#endif
}

// r11 structure (one seq per wave, 4 independent waves/block) with ONE delta:
// P never goes to LDS. S = H H^T is symmetric, so the PV A-fragment
// P[16ti+c16][16tj+4g+e] equals a value already held in-lane (reg e of
// SS[tj][ti]); softmax runs along the transposed axis (g-group reduce via
// shfl_xor 16/32), P is pre-scaled by 1/sum and packed in-register, and PV
// uses 16x16x16 MFMA (K-slot per lane = 4g+e — exactly our in-lane layout).
__global__ __launch_bounds__(256, 4)
void seq_attn_kernel(const float* __restrict__ h,
                     const int* __restrict__ sse,  // int32 (JAX x64 disabled)
                     float* __restrict__ out) {
  __shared__ unsigned short HsAll[WAVES * 64 * STR];  // 36.9 KB/block

  const int tid = threadIdx.x;
  const int w = tid >> 6;
  const int lane = tid & 63;
  unsigned short* Hs = HsAll + w * (64 * STR);  // wave-private slice

  const int s = blockIdx.x + gridDim.x * w;
  const int start = sse[2 * s];
  const int L = sse[2 * s + 1] - start;
  const int nt = (L + 15) >> 4;  // live 16-row tiles
  const int g = lane >> 4;
  const int c16 = lane & 15;

  // ---- stage H fp32->bf16 (r11 verbatim): rows >= L exact zero ----
  {
    const float* src = h + (size_t)start * D;
    const int c4 = c16 * 4;
    float4 va[8], vb[8];
    #pragma unroll
    for (int it = 0; it < 8; ++it) {
      const int r = it * 4 + g;
      const int rc = (r < L) ? r : 0;
      va[it] = *(const float4*)(src + rc * D + c4);
    }
    const bool hi = (L > 32);
    #pragma unroll
    for (int it = 0; it < 8; ++it) {
      const int r = 32 + it * 4 + g;
      const int rc = (r < L) ? r : 0;
      vb[it] = hi ? *(const float4*)(src + rc * D + c4) : make_float4(0.f, 0.f, 0.f, 0.f);
    }
    #pragma unroll
    for (int it = 0; it < 8; ++it) {
      const int r = it * 4 + g;
      const bool ok = (r < L);
      ushort4 wv;
      wv.x = ok ? f2bf(va[it].x) : (unsigned short)0;
      wv.y = ok ? f2bf(va[it].y) : (unsigned short)0;
      wv.z = ok ? f2bf(va[it].z) : (unsigned short)0;
      wv.w = ok ? f2bf(va[it].w) : (unsigned short)0;
      *(ushort4*)&Hs[r * STR + c4] = wv;
    }
    #pragma unroll
    for (int it = 0; it < 8; ++it) {
      const int r = 32 + it * 4 + g;
      const bool ok = (r < L);
      ushort4 wv;
      wv.x = ok ? f2bf(vb[it].x) : (unsigned short)0;
      wv.y = ok ? f2bf(vb[it].y) : (unsigned short)0;
      wv.z = ok ? f2bf(vb[it].z) : (unsigned short)0;
      wv.w = ok ? f2bf(vb[it].w) : (unsigned short)0;
      *(ushort4*)&Hs[r * STR + c4] = wv;
    }
  }
  LDSWAIT();

  // ---- hf: A-layout fragments (both operands of S = H H^T) — r11 verbatim ----
  bf16x8 hf[4][2];
  #pragma unroll
  for (int t = 0; t < 4; ++t)
    #pragma unroll
    for (int kb = 0; kb < 2; ++kb)
      hf[t][kb] = *(const bf16x8*)&Hs[(t * 16 + c16) * STR + kb * 32 + g * 8];

  // ---- QK^T: full S in registers. SS[a][b][r] = S[16a+4g+r][16b+c16] ----
  f32x4 SS[4][4];
  #pragma unroll
  for (int a = 0; a < 4; ++a)
    #pragma unroll
    for (int b = 0; b < 4; ++b) {
      f32x4 z = {0.f, 0.f, 0.f, 0.f};
      SS[a][b] = z;
    }
  #pragma unroll
  for (int a = 0; a < 4; ++a)
    if (a < nt)
      #pragma unroll
      for (int b = 0; b < 4; ++b)
        if (b < nt)
          #pragma unroll
          for (int kb = 0; kb < 2; ++kb)
            SS[a][b] = __builtin_amdgcn_mfma_f32_16x16x32_bf16(
                hf[a][kb], hf[b][kb], SS[a][b], 0, 0, 0);

  // ---- transposed softmax + in-register P (PV A-fragments) ----
  // View ti: row q = 16ti + c16. SS[tj][ti][e] = S[16tj+4g+e][16ti+c16]
  // = S[q][m] with m = 16tj+4g+e (symmetry). Reduce over (tj,e) locally,
  // then across the 4-lane g-group (lane^16, lane^32).
  u32x2 pb[4][4];  // packed bf16 A-frag: P[q][16tj+4g+e] * inv_q, e=0..3
  #pragma unroll
  for (int ti = 0; ti < 4; ++ti) {
    if (ti >= nt) continue;
    float lm = -1e30f;
    #pragma unroll
    for (int tj = 0; tj < 4; ++tj) {
      if (tj >= nt) continue;
      #pragma unroll
      for (int e = 0; e < 4; ++e) {
        const int m = 16 * tj + 4 * g + e;
        const float v = (m < L) ? SS[tj][ti][e] : -1e30f;  // mask pad keys
        SS[tj][ti][e] = v;
        lm = fmaxf(lm, v);
      }
    }
    lm = fmaxf(lm, __shfl_xor(lm, 16, 64));
    lm = fmaxf(lm, __shfl_xor(lm, 32, 64));
    float sum = 0.f;
    #pragma unroll
    for (int tj = 0; tj < 4; ++tj) {
      if (tj >= nt) continue;
      #pragma unroll
      for (int e = 0; e < 4; ++e) {
        const float p = __expf(SS[tj][ti][e] - lm);  // masked -> exp(-huge) = 0
        SS[tj][ti][e] = p;
        sum += p;
      }
    }
    sum += __shfl_xor(sum, 16, 64);
    sum += __shfl_xor(sum, 32, 64);
    const float inv = 1.0f / sum;  // pre-scale P (normalization folded in)
    #pragma unroll
    for (int tj = 0; tj < 4; ++tj) {
      if (tj >= nt) continue;
      u32x2 pw;
      pw[0] = (unsigned)f2bf(SS[tj][ti][0] * inv) | ((unsigned)f2bf(SS[tj][ti][1] * inv) << 16);
      pw[1] = (unsigned)f2bf(SS[tj][ti][2] * inv) | ((unsigned)f2bf(SS[tj][ti][3] * inv) << 16);
      pb[ti][tj] = pw;
    }
  }

  // ---- vfB: B-frags for K=16 PV, loaded AFTER softmax (VGPR peak control).
  // B[k=4g+e][j=c16] = V[16tj+4g+e][16dt+c16]; pad rows are exact 0.
  bf16x4 vfB[4][4];
  #pragma unroll
  for (int tj = 0; tj < 4; ++tj) {
    if (tj >= nt) continue;
    #pragma unroll
    for (int dt = 0; dt < 4; ++dt) {
      u32x2 wv;
      const unsigned e0 = Hs[(16 * tj + 4 * g + 0) * STR + 16 * dt + c16];
      const unsigned e1 = Hs[(16 * tj + 4 * g + 1) * STR + 16 * dt + c16];
      const unsigned e2 = Hs[(16 * tj + 4 * g + 2) * STR + 16 * dt + c16];
      const unsigned e3 = Hs[(16 * tj + 4 * g + 3) * STR + 16 * dt + c16];
      wv[0] = e0 | (e1 << 16);
      wv[1] = e2 | (e3 << 16);
      vfB[tj][dt] = __builtin_bit_cast(bf16x4, wv);
    }
  }

  // ---- PV (K=16) + store. C-layout: O[16ti+4g+r][16dt+c16]; P pre-scaled ----
  #pragma unroll
  for (int ti = 0; ti < 4; ++ti) {
    if (ti >= nt) continue;
    #pragma unroll
    for (int dt = 0; dt < 4; ++dt) {
      f32x4 o = {0.f, 0.f, 0.f, 0.f};
      #pragma unroll
      for (int tj = 0; tj < 4; ++tj)
        if (tj < nt)
          o = mfma16(__builtin_bit_cast(bf16x4, pb[ti][tj]), vfB[tj][dt], o);
      #pragma unroll
      for (int r = 0; r < 4; ++r) {
        const int row = ti * 16 + g * 4 + r;
        if (row < L)
          out[(size_t)(start + row) * D + dt * 16 + c16] = o[r];
      }
    }
  }
}

extern "C" void kernel_launch(void* const* d_in, const int* in_sizes, int n_in,
                              void* d_out, int out_size, void* d_ws, size_t ws_size,
                              hipStream_t stream) {
  const float* h = (const float*)d_in[0];
  const int* sse = (const int*)d_in[1];
  float* out = (float*)d_out;
  const int nseq = in_sizes[1] / 2;  // 4096
  const int nblk = nseq / WAVES;     // 1024
  seq_attn_kernel<<<nblk, 64 * WAVES, 0, stream>>>(h, sse, out);
}